// Round 5
// baseline (65.131 us; speedup 1.0000x reference)
//
#include <hip/hip_runtime.h>

// Chamfer distance, B=4, N=8192, fp32 3-D points, MI355X.
// Round 5: two row-min-only passes (no col-min trees, no LDS atomics).
//   dist tile via one v_mfma_f32_32x32x16_f16, K-slot packed (verified r3/r4):
//     A g0={hx,hy,hz,hx,hy,hz,lx,ly}       g1={lz,sh,sl,1,1,0,0,0}
//     B g0={-2hx,-2hy,-2hz,-2lx,-2ly,-2lz,-2hx,-2hy}  g1={-2hz,1,1,sh,sl,0,0,0}
//   Epilogue per B-tile-pair: rowmin = min3(rowmin, acc0, acc1) (elementwise).
//   A-register-blocked x2: each B fragment feeds 2 MFMAs.
//   __syncthreads every 16 B-tiles keeps the block's 8 waves L1-coherent.

typedef _Float16 half8  __attribute__((ext_vector_type(8)));
typedef float    f32x16 __attribute__((ext_vector_type(16)));

#define NPTS   8192
#define NB     4
#define TILES  256          // 32-point tiles per (cloud,batch)
#define SPLITS 4            // B-range splits per direction
#define TPW    (TILES / SPLITS)   // 64 B-tiles per sweep

// ---------- prep: BOTH clouds into B-role fragments ----------
// wsB layout: [cloud][b][tile][lane], cloud0=pc1, cloud1=pc2.
__global__ __launch_bounds__(256) void chamfer_prep(
    const float* __restrict__ pc1, const float* __restrict__ pc2,
    half8* __restrict__ wsB)
{
    const int tid   = blockIdx.x * 256 + threadIdx.x;  // 0..131071
    const int lane  = tid & 63;
    const int tile  = (tid >> 6) & (TILES - 1);
    const int b     = (tid >> 14) & (NB - 1);
    const int cloud = tid >> 16;

    const float* pc = cloud ? pc2 : pc1;
    const int col = lane & 31, g = lane >> 5;

    const float* Q = pc + ((size_t)b * NPTS + tile * 32 + col) * 3;
    const float qx = Q[0], qy = Q[1], qz = Q[2];

    const _Float16 hx = (_Float16)qx, hy = (_Float16)qy, hz = (_Float16)qz;
    const _Float16 lx = (_Float16)(qx - (float)hx);
    const _Float16 ly = (_Float16)(qy - (float)hy);
    const _Float16 lz = (_Float16)(qz - (float)hz);
    const float sq = fmaf(qx, qx, fmaf(qy, qy, qz * qz));
    const _Float16 sh = (_Float16)sq;
    const _Float16 sl = (_Float16)(sq - (float)sh);

    const _Float16 nhx = (_Float16)(-2.0f * (float)hx);
    const _Float16 nhy = (_Float16)(-2.0f * (float)hy);
    const _Float16 nhz = (_Float16)(-2.0f * (float)hz);
    const _Float16 nlx = (_Float16)(-2.0f * (float)lx);
    const _Float16 nly = (_Float16)(-2.0f * (float)ly);
    const _Float16 nlz = (_Float16)(-2.0f * (float)lz);
    const _Float16 one = (_Float16)1.0f, zz = (_Float16)0.0f;

    half8 v;
    if (g == 0) v = (half8){nhx, nhy, nhz, nlx, nly, nlz, nhx, nhy};
    else        v = (half8){nhz, one, one, sh,  sl,  zz,  zz,  zz};
    wsB[tid] = v;
}

// ---------- main: 512 blocks x 512 thr ----------
// block = (dir, b, qsplit, ptile-of-512); wave = 64 p-rows (2 A-tiles).
__global__ __launch_bounds__(512, 4) void chamfer_main(
    const float* __restrict__ pc1, const float* __restrict__ pc2,
    const half8* __restrict__ wsB, float* __restrict__ ws_row)
{
    int bid = blockIdx.x;
    const int pt  = bid & 15;            bid >>= 4;
    const int qs  = bid & (SPLITS - 1);  bid >>= 2;
    const int b   = bid & (NB - 1);      bid >>= 2;
    const int dir = bid;

    const int tid = threadIdx.x;
    const int w = tid >> 6, lane = tid & 63;
    const int col = lane & 31, g = lane >> 5;
    const int pbase = pt * 512 + w * 64;       // this wave: rows pbase..pbase+63

    const float* Acl = dir ? pc2 : pc1;        // row side
    const int    bcl = dir ? 0 : 1;            // col side (B-role cloud)

    const _Float16 one = (_Float16)1.0f, zz = (_Float16)0.0f;

    // Two A fragments (rows pbase+col and pbase+32+col).
    half8 a0, a1;
    #pragma unroll
    for (int h = 0; h < 2; ++h) {
        const float* P = Acl + ((size_t)b * NPTS + pbase + h * 32 + col) * 3;
        const float px = P[0], py = P[1], pz = P[2];
        const _Float16 hx = (_Float16)px, hy = (_Float16)py, hz = (_Float16)pz;
        const _Float16 lx = (_Float16)(px - (float)hx);
        const _Float16 ly = (_Float16)(py - (float)hy);
        const _Float16 lz = (_Float16)(pz - (float)hz);
        const float sq1 = fmaf(px, px, fmaf(py, py, pz * pz));
        const _Float16 sh = (_Float16)sq1;
        const _Float16 sl = (_Float16)(sq1 - (float)sh);
        half8 a;
        if (g == 0) a = (half8){hx, hy, hz, hx, hy, hz, lx, ly};
        else        a = (half8){lz, sh, sl, one, one, zz, zz, zz};
        if (h == 0) a0 = a; else a1 = a;
    }

    const half8* Bb = wsB + (((size_t)bcl * NB + b) * TILES + qs * TPW) * 64 + lane;

    f32x16 rowmin0, rowmin1;
    #pragma unroll
    for (int r = 0; r < 16; ++r) { rowmin0[r] = 3.402823466e+38f;
                                   rowmin1[r] = 3.402823466e+38f; }
    const f32x16 zero16 = {};

    half8 bf0 = Bb[0];
    half8 bf1 = Bb[64];

    for (int tc = 0; tc < TPW; tc += 16) {
        #pragma unroll
        for (int t = 0; t < 16; t += 2) {
            const int tg = tc + t;
            const int tn = (tg + 2 < TPW) ? tg + 2 : TPW - 2;
            const half8 n0 = Bb[(size_t)tn * 64];
            const half8 n1 = Bb[(size_t)tn * 64 + 64];

            const f32x16 acc00 = __builtin_amdgcn_mfma_f32_32x32x16_f16(a0, bf0, zero16, 0, 0, 0);
            const f32x16 acc01 = __builtin_amdgcn_mfma_f32_32x32x16_f16(a0, bf1, zero16, 0, 0, 0);
            rowmin0 = __builtin_elementwise_min(rowmin0,
                       __builtin_elementwise_min(acc00, acc01));   // -> v_min3

            const f32x16 acc10 = __builtin_amdgcn_mfma_f32_32x32x16_f16(a1, bf0, zero16, 0, 0, 0);
            const f32x16 acc11 = __builtin_amdgcn_mfma_f32_32x32x16_f16(a1, bf1, zero16, 0, 0, 0);
            rowmin1 = __builtin_elementwise_min(rowmin1,
                       __builtin_elementwise_min(acc10, acc11));

            bf0 = n0; bf1 = n1;
        }
        __syncthreads();   // bound wave drift -> keep shared B stream in L1
    }

    // Cross-column min (32 cols) + store. row map: (r&3)+8*(r>>2)+4*g (m74/m101).
    const size_t obase = (((size_t)dir * NB + b) * SPLITS + qs) * NPTS + pbase;
    #pragma unroll
    for (int r = 0; r < 16; ++r) {
        float v = rowmin0[r];
        v = fminf(v, __shfl_xor(v, 1, 64));
        v = fminf(v, __shfl_xor(v, 2, 64));
        v = fminf(v, __shfl_xor(v, 4, 64));
        v = fminf(v, __shfl_xor(v, 8, 64));
        v = fminf(v, __shfl_xor(v, 16, 64));
        float u = rowmin1[r];
        u = fminf(u, __shfl_xor(u, 1, 64));
        u = fminf(u, __shfl_xor(u, 2, 64));
        u = fminf(u, __shfl_xor(u, 4, 64));
        u = fminf(u, __shfl_xor(u, 16, 64));
        u = fminf(u, __shfl_xor(u, 8, 64));
        if (col == 0) {
            const int row = (r & 3) + 8 * (r >> 2) + 4 * g;
            ws_row[obase + row]      = v;
            ws_row[obase + 32 + row] = u;
        }
    }
}

// ---------- final: one block per batch ----------
__global__ __launch_bounds__(256) void chamfer_final(
    const float* __restrict__ ws_row, float* __restrict__ out)
{
    const int b = blockIdx.x;
    float sum = 0.0f;

    #pragma unroll
    for (int dir = 0; dir < 2; ++dir) {
        const float* base = ws_row + ((size_t)dir * NB + b) * SPLITS * NPTS;
        for (int p = threadIdx.x; p < NPTS; p += 256) {
            const float m = fminf(fminf(base[p],            base[NPTS + p]),
                                  fminf(base[2 * NPTS + p], base[3 * NPTS + p]));
            sum += m;
        }
    }

    for (int off = 32; off; off >>= 1) sum += __shfl_down(sum, off, 64);
    __shared__ float red[4];
    if (!(threadIdx.x & 63)) red[threadIdx.x >> 6] = sum;
    __syncthreads();
    if (!threadIdx.x)
        out[b] = (red[0] + red[1] + red[2] + red[3]) * (1.0f / (float)NPTS);
}

extern "C" void kernel_launch(void* const* d_in, const int* in_sizes, int n_in,
                              void* d_out, int out_size, void* d_ws, size_t ws_size,
                              hipStream_t stream)
{
    const float* pc1 = (const float*)d_in[0];
    const float* pc2 = (const float*)d_in[1];
    float* out = (float*)d_out;

    char* ws = (char*)d_ws;
    half8* wsB    = (half8*)ws;                 // 2 cl * 4 b * 256 t * 64 * 16B = 2 MiB
    float* ws_row = (float*)(ws + (2 << 20));   // 2 * 4 * SPLITS * 8192 * 4B = 1 MiB

    chamfer_prep<<<512, 256, 0, stream>>>(pc1, pc2, wsB);
    chamfer_main<<<512, 512, 0, stream>>>(pc1, pc2, wsB, ws_row);
    chamfer_final<<<NB, 256, 0, stream>>>(ws_row, out);
}

// Round 6
// 49.708 us; speedup vs baseline: 1.3103x; 1.3103x over previous
//
#include <hip/hip_runtime.h>

// Chamfer distance, B=4, N=8192, fp32 3-D points, MI355X.
// Round 6: same verified MFMA K-slot algorithm (r3-r5), fixing round-5's
// regalloc disaster:
//  - 256-thr blocks, __launch_bounds__(256,3): ~170-reg budget so the 4 accs
//    + 2 rowmins stay in arch VGPRs (r5: 64-reg cap -> AGPR spill -> 16
//    v_accvgpr_read per fold, ~3x VALU inflation)
//  - compile-time prefetch offsets inside a 16-tile window (no per-iter
//    clamp/cndmask address math); 2-tile overrun pads into ws_row (unused)
//  - 256-block reduce stage so no kernel reads 1 MB with 4 blocks

typedef _Float16 half8  __attribute__((ext_vector_type(8)));
typedef float    f32x16 __attribute__((ext_vector_type(16)));

#define NPTS   8192
#define NB     4
#define TILES  256                 // 32-point tiles per (cloud,batch)
#define SPLITS 4                   // B-range splits per direction
#define TPW    (TILES / SPLITS)    // 64 B-tiles per sweep
#define WIN    16                  // tiles per L1-coherence window

// ---------- prep: BOTH clouds into B-role fragments ----------
// wsB layout: [cloud][b][tile][lane], cloud0=pc1, cloud1=pc2.
__global__ __launch_bounds__(256) void chamfer_prep(
    const float* __restrict__ pc1, const float* __restrict__ pc2,
    half8* __restrict__ wsB)
{
    const int tid   = blockIdx.x * 256 + threadIdx.x;  // 0..131071
    const int lane  = tid & 63;
    const int tile  = (tid >> 6) & (TILES - 1);
    const int b     = (tid >> 14) & (NB - 1);
    const int cloud = tid >> 16;

    const float* pc = cloud ? pc2 : pc1;
    const int col = lane & 31, g = lane >> 5;

    const float* Q = pc + ((size_t)b * NPTS + tile * 32 + col) * 3;
    const float qx = Q[0], qy = Q[1], qz = Q[2];

    const _Float16 hx = (_Float16)qx, hy = (_Float16)qy, hz = (_Float16)qz;
    const _Float16 lx = (_Float16)(qx - (float)hx);
    const _Float16 ly = (_Float16)(qy - (float)hy);
    const _Float16 lz = (_Float16)(qz - (float)hz);
    const float sq = fmaf(qx, qx, fmaf(qy, qy, qz * qz));
    const _Float16 sh = (_Float16)sq;
    const _Float16 sl = (_Float16)(sq - (float)sh);

    const _Float16 nhx = (_Float16)(-2.0f * (float)hx);
    const _Float16 nhy = (_Float16)(-2.0f * (float)hy);
    const _Float16 nhz = (_Float16)(-2.0f * (float)hz);
    const _Float16 nlx = (_Float16)(-2.0f * (float)lx);
    const _Float16 nly = (_Float16)(-2.0f * (float)ly);
    const _Float16 nlz = (_Float16)(-2.0f * (float)lz);
    const _Float16 one = (_Float16)1.0f, zz = (_Float16)0.0f;

    half8 v;
    if (g == 0) v = (half8){nhx, nhy, nhz, nlx, nly, nlz, nhx, nhy};
    else        v = (half8){nhz, one, one, sh,  sl,  zz,  zz,  zz};
    wsB[tid] = v;
}

// ---------- main: 1024 blocks x 256 thr ----------
// block = (dir, b, qsplit, ptile-of-256); wave = 64 p-rows (2 A-tiles).
__global__ __launch_bounds__(256, 3) void chamfer_main(
    const float* __restrict__ pc1, const float* __restrict__ pc2,
    const half8* __restrict__ wsB, float* __restrict__ ws_row)
{
    int bid = blockIdx.x;
    const int pt  = bid & 31;            bid >>= 5;
    const int qs  = bid & (SPLITS - 1);  bid >>= 2;
    const int b   = bid & (NB - 1);      bid >>= 2;
    const int dir = bid;

    const int tid = threadIdx.x;
    const int w = tid >> 6, lane = tid & 63;
    const int col = lane & 31, g = lane >> 5;
    const int pbase = pt * 256 + w * 64;       // this wave: rows pbase..pbase+63

    const float* Acl = dir ? pc2 : pc1;        // row side
    const int    bcl = dir ? 0 : 1;            // col side (B-role cloud)

    const _Float16 one = (_Float16)1.0f, zz = (_Float16)0.0f;

    // Two A fragments (rows pbase+col and pbase+32+col).
    half8 a0, a1;
    #pragma unroll
    for (int h = 0; h < 2; ++h) {
        const float* P = Acl + ((size_t)b * NPTS + pbase + h * 32 + col) * 3;
        const float px = P[0], py = P[1], pz = P[2];
        const _Float16 hx = (_Float16)px, hy = (_Float16)py, hz = (_Float16)pz;
        const _Float16 lx = (_Float16)(px - (float)hx);
        const _Float16 ly = (_Float16)(py - (float)hy);
        const _Float16 lz = (_Float16)(pz - (float)hz);
        const float sq1 = fmaf(px, px, fmaf(py, py, pz * pz));
        const _Float16 sh = (_Float16)sq1;
        const _Float16 sl = (_Float16)(sq1 - (float)sh);
        half8 a;
        if (g == 0) a = (half8){hx, hy, hz, hx, hy, hz, lx, ly};
        else        a = (half8){lz, sh, sl, one, one, zz, zz, zz};
        if (h == 0) a0 = a; else a1 = a;
    }

    const half8* Bw = wsB + (((size_t)bcl * NB + b) * TILES + qs * TPW) * 64 + lane;

    f32x16 rowmin0, rowmin1;
    #pragma unroll
    for (int r = 0; r < 16; ++r) { rowmin0[r] = 3.402823466e+38f;
                                   rowmin1[r] = 3.402823466e+38f; }
    const f32x16 zero16 = {};

    half8 bf0 = Bw[0];
    half8 bf1 = Bw[64];

    for (int tc = 0; tc < TPW; tc += WIN) {
        #pragma unroll
        for (int t = 0; t < WIN; t += 2) {
            // compile-time offsets; final window overruns 2 tiles into ws_row
            // (loaded but never consumed)
            const half8 n0 = Bw[(t + 2) * 64];
            const half8 n1 = Bw[(t + 3) * 64];

            const f32x16 acc00 = __builtin_amdgcn_mfma_f32_32x32x16_f16(a0, bf0, zero16, 0, 0, 0);
            const f32x16 acc01 = __builtin_amdgcn_mfma_f32_32x32x16_f16(a0, bf1, zero16, 0, 0, 0);
            const f32x16 acc10 = __builtin_amdgcn_mfma_f32_32x32x16_f16(a1, bf0, zero16, 0, 0, 0);
            const f32x16 acc11 = __builtin_amdgcn_mfma_f32_32x32x16_f16(a1, bf1, zero16, 0, 0, 0);

            rowmin0 = __builtin_elementwise_min(rowmin0,
                       __builtin_elementwise_min(acc00, acc01));   // -> v_min3
            rowmin1 = __builtin_elementwise_min(rowmin1,
                       __builtin_elementwise_min(acc10, acc11));

            bf0 = n0; bf1 = n1;
        }
        Bw += WIN * 64;
        __syncthreads();   // bound wave drift -> shared B window stays in L1
    }

    // Cross-column min (32 cols) + store. row map: (r&3)+8*(r>>2)+4*g (m74/m101).
    const size_t obase = (((size_t)dir * NB + b) * SPLITS + qs) * NPTS + pbase;
    #pragma unroll
    for (int r = 0; r < 16; ++r) {
        float v = rowmin0[r];
        v = fminf(v, __shfl_xor(v, 1, 64));
        v = fminf(v, __shfl_xor(v, 2, 64));
        v = fminf(v, __shfl_xor(v, 4, 64));
        v = fminf(v, __shfl_xor(v, 8, 64));
        v = fminf(v, __shfl_xor(v, 16, 64));
        float u = rowmin1[r];
        u = fminf(u, __shfl_xor(u, 1, 64));
        u = fminf(u, __shfl_xor(u, 2, 64));
        u = fminf(u, __shfl_xor(u, 4, 64));
        u = fminf(u, __shfl_xor(u, 8, 64));
        u = fminf(u, __shfl_xor(u, 16, 64));
        if (col == 0) {
            const int row = (r & 3) + 8 * (r >> 2) + 4 * g;
            ws_row[obase + row]      = v;
            ws_row[obase + 32 + row] = u;
        }
    }
}

// ---------- reduce: 256 blocks; min over 4 splits, block partial sums ----------
__global__ __launch_bounds__(256) void chamfer_reduce(
    const float* __restrict__ ws_row, float* __restrict__ partial)
{
    int bid = blockIdx.x;                    // 2 dir x 4 b x 32 slices
    const int sl  = bid & 31; bid >>= 5;
    const int b   = bid & 3;  bid >>= 2;
    const int dir = bid;

    const int p = sl * 256 + threadIdx.x;
    const float* base = ws_row + (((size_t)dir * NB + b) * SPLITS) * NPTS + p;
    float sum = fminf(fminf(base[0],        base[NPTS]),
                      fminf(base[2 * NPTS], base[3 * NPTS]));

    for (int off = 32; off; off >>= 1) sum += __shfl_down(sum, off, 64);
    __shared__ float red[4];
    if (!(threadIdx.x & 63)) red[threadIdx.x >> 6] = sum;
    __syncthreads();
    if (!threadIdx.x)
        partial[blockIdx.x] = red[0] + red[1] + red[2] + red[3];
}

// ---------- final: 4 blocks x 64 thr; each b sums its 64 partials ----------
__global__ __launch_bounds__(64) void chamfer_final(
    const float* __restrict__ partial, float* __restrict__ out)
{
    const int b = blockIdx.x, t = threadIdx.x;
    const int dir = t >> 5, sl = t & 31;
    float v = partial[(((size_t)dir * NB + b) << 5) + sl];
    for (int off = 32; off; off >>= 1) v += __shfl_down(v, off, 64);
    if (!t) out[b] = v * (1.0f / (float)NPTS);
}

extern "C" void kernel_launch(void* const* d_in, const int* in_sizes, int n_in,
                              void* d_out, int out_size, void* d_ws, size_t ws_size,
                              hipStream_t stream)
{
    const float* pc1 = (const float*)d_in[0];
    const float* pc2 = (const float*)d_in[1];
    float* out = (float*)d_out;

    char* ws = (char*)d_ws;
    half8* wsB     = (half8*)ws;                         // 2 MiB (+2-tile overrun pad into ws_row)
    float* ws_row  = (float*)(ws + (2 << 20));           // 1 MiB
    float* partial = (float*)(ws + (3 << 20));           // 1 KiB

    chamfer_prep<<<512, 256, 0, stream>>>(pc1, pc2, wsB);
    chamfer_main<<<1024, 256, 0, stream>>>(pc1, pc2, wsB, ws_row);
    chamfer_reduce<<<256, 256, 0, stream>>>(ws_row, partial);
    chamfer_final<<<NB, 64, 0, stream>>>(partial, out);
}

// Round 7
// 37.185 us; speedup vs baseline: 1.7515x; 1.3368x over previous
//
#include <hip/hip_runtime.h>

// Chamfer distance, B=4, N=8192, fp32 3-D points, MI355X.
// Round 7: force MFMA accumulators into arch VGPRs via inline asm with
// "=&v" constraints (r5/r6: intrinsic results went to AGPRs; VALU can't
// source AGPRs -> 16 v_accvgpr_read per acc per fold = 3x VALU inflation,
// main stuck at 43.4us). Fold is then pure v_min3 on VGPRs.
// Hazard discipline (hand MFMA => compiler won't insert waits):
//   4x MFMA issue -> sched_barrier(0) -> 2x s_nop 7 -> sched_barrier(0)
//   -> min3 folds (first read of acc00 is >=40 cyc after its issue).

typedef _Float16 half8  __attribute__((ext_vector_type(8)));
typedef float    f32x16 __attribute__((ext_vector_type(16)));

#define NPTS   8192
#define NB     4
#define TILES  256                 // 32-point tiles per (cloud,batch)
#define SPLITS 4                   // B-range splits per direction
#define TPW    (TILES / SPLITS)    // 64 B-tiles per sweep
#define WIN    16                  // tiles per L1-coherence window

#define MFMA_V(d, a, b, c)                                             \
    asm("v_mfma_f32_32x32x16_f16 %0, %1, %2, %3"                       \
        : "=&v"(d) : "v"(a), "v"(b), "v"(c))

// ---------- prep: BOTH clouds into B-role fragments ----------
// wsB layout: [cloud][b][tile][lane], cloud0=pc1, cloud1=pc2.
__global__ __launch_bounds__(256) void chamfer_prep(
    const float* __restrict__ pc1, const float* __restrict__ pc2,
    half8* __restrict__ wsB)
{
    const int tid   = blockIdx.x * 256 + threadIdx.x;  // 0..131071
    const int lane  = tid & 63;
    const int tile  = (tid >> 6) & (TILES - 1);
    const int b     = (tid >> 14) & (NB - 1);
    const int cloud = tid >> 16;

    const float* pc = cloud ? pc2 : pc1;
    const int col = lane & 31, g = lane >> 5;

    const float* Q = pc + ((size_t)b * NPTS + tile * 32 + col) * 3;
    const float qx = Q[0], qy = Q[1], qz = Q[2];

    const _Float16 hx = (_Float16)qx, hy = (_Float16)qy, hz = (_Float16)qz;
    const _Float16 lx = (_Float16)(qx - (float)hx);
    const _Float16 ly = (_Float16)(qy - (float)hy);
    const _Float16 lz = (_Float16)(qz - (float)hz);
    const float sq = fmaf(qx, qx, fmaf(qy, qy, qz * qz));
    const _Float16 sh = (_Float16)sq;
    const _Float16 sl = (_Float16)(sq - (float)sh);

    const _Float16 nhx = (_Float16)(-2.0f * (float)hx);
    const _Float16 nhy = (_Float16)(-2.0f * (float)hy);
    const _Float16 nhz = (_Float16)(-2.0f * (float)hz);
    const _Float16 nlx = (_Float16)(-2.0f * (float)lx);
    const _Float16 nly = (_Float16)(-2.0f * (float)ly);
    const _Float16 nlz = (_Float16)(-2.0f * (float)lz);
    const _Float16 one = (_Float16)1.0f, zz = (_Float16)0.0f;

    half8 v;
    if (g == 0) v = (half8){nhx, nhy, nhz, nlx, nly, nlz, nhx, nhy};
    else        v = (half8){nhz, one, one, sh,  sl,  zz,  zz,  zz};
    wsB[tid] = v;
}

// ---------- main: 1024 blocks x 256 thr ----------
// block = (dir, b, qsplit, ptile-of-256); wave = 64 p-rows (2 A-tiles).
__global__ __launch_bounds__(256, 3) void chamfer_main(
    const float* __restrict__ pc1, const float* __restrict__ pc2,
    const half8* __restrict__ wsB, float* __restrict__ ws_row)
{
    int bid = blockIdx.x;
    const int pt  = bid & 31;            bid >>= 5;
    const int qs  = bid & (SPLITS - 1);  bid >>= 2;
    const int b   = bid & (NB - 1);      bid >>= 2;
    const int dir = bid;

    const int tid = threadIdx.x;
    const int w = tid >> 6, lane = tid & 63;
    const int col = lane & 31, g = lane >> 5;
    const int pbase = pt * 256 + w * 64;       // this wave: rows pbase..pbase+63

    const float* Acl = dir ? pc2 : pc1;        // row side
    const int    bcl = dir ? 0 : 1;            // col side (B-role cloud)

    const _Float16 one = (_Float16)1.0f, zz = (_Float16)0.0f;

    // Two A fragments (rows pbase+col and pbase+32+col).
    half8 a0, a1;
    #pragma unroll
    for (int h = 0; h < 2; ++h) {
        const float* P = Acl + ((size_t)b * NPTS + pbase + h * 32 + col) * 3;
        const float px = P[0], py = P[1], pz = P[2];
        const _Float16 hx = (_Float16)px, hy = (_Float16)py, hz = (_Float16)pz;
        const _Float16 lx = (_Float16)(px - (float)hx);
        const _Float16 ly = (_Float16)(py - (float)hy);
        const _Float16 lz = (_Float16)(pz - (float)hz);
        const float sq1 = fmaf(px, px, fmaf(py, py, pz * pz));
        const _Float16 sh = (_Float16)sq1;
        const _Float16 sl = (_Float16)(sq1 - (float)sh);
        half8 a;
        if (g == 0) a = (half8){hx, hy, hz, hx, hy, hz, lx, ly};
        else        a = (half8){lz, sh, sl, one, one, zz, zz, zz};
        if (h == 0) a0 = a; else a1 = a;
    }

    const half8* Bw = wsB + (((size_t)bcl * NB + b) * TILES + qs * TPW) * 64 + lane;

    f32x16 rowmin0, rowmin1;
    #pragma unroll
    for (int r = 0; r < 16; ++r) { rowmin0[r] = 3.402823466e+38f;
                                   rowmin1[r] = 3.402823466e+38f; }
    f32x16 zero16;
    #pragma unroll
    for (int r = 0; r < 16; ++r) zero16[r] = 0.0f;

    half8 bf0 = Bw[0];
    half8 bf1 = Bw[64];

    for (int tc = 0; tc < TPW; tc += WIN) {
        #pragma unroll
        for (int t = 0; t < WIN; t += 2) {
            // compile-time offsets; final window overruns 2 tiles into ws_row
            // (loaded but never consumed)
            const half8 n0 = Bw[(t + 2) * 64];
            const half8 n1 = Bw[(t + 3) * 64];

            f32x16 acc00, acc01, acc10, acc11;
            MFMA_V(acc00, a0, bf0, zero16);
            MFMA_V(acc01, a0, bf1, zero16);
            MFMA_V(acc10, a1, bf0, zero16);
            MFMA_V(acc11, a1, bf1, zero16);

            // pin: no VALU read of accs until >= 16 nops after last issue
            __builtin_amdgcn_sched_barrier(0);
            asm volatile("s_nop 7\n\ts_nop 7");
            __builtin_amdgcn_sched_barrier(0);

            #pragma unroll
            for (int r = 0; r < 16; ++r)
                rowmin0[r] = fminf(fminf(acc00[r], acc01[r]), rowmin0[r]);
            #pragma unroll
            for (int r = 0; r < 16; ++r)
                rowmin1[r] = fminf(fminf(acc10[r], acc11[r]), rowmin1[r]);

            bf0 = n0; bf1 = n1;
        }
        Bw += WIN * 64;
        __syncthreads();   // bound wave drift -> shared B window stays in L1
    }

    // Cross-column min (32 cols) + store. row map: (r&3)+8*(r>>2)+4*g (m74/m101).
    const size_t obase = (((size_t)dir * NB + b) * SPLITS + qs) * NPTS + pbase;
    #pragma unroll
    for (int r = 0; r < 16; ++r) {
        float v = rowmin0[r];
        v = fminf(v, __shfl_xor(v, 1, 64));
        v = fminf(v, __shfl_xor(v, 2, 64));
        v = fminf(v, __shfl_xor(v, 4, 64));
        v = fminf(v, __shfl_xor(v, 8, 64));
        v = fminf(v, __shfl_xor(v, 16, 64));
        float u = rowmin1[r];
        u = fminf(u, __shfl_xor(u, 1, 64));
        u = fminf(u, __shfl_xor(u, 2, 64));
        u = fminf(u, __shfl_xor(u, 4, 64));
        u = fminf(u, __shfl_xor(u, 8, 64));
        u = fminf(u, __shfl_xor(u, 16, 64));
        if (col == 0) {
            const int row = (r & 3) + 8 * (r >> 2) + 4 * g;
            ws_row[obase + row]      = v;
            ws_row[obase + 32 + row] = u;
        }
    }
}

// ---------- reduce: 256 blocks; min over 4 splits, block partial sums ----------
__global__ __launch_bounds__(256) void chamfer_reduce(
    const float* __restrict__ ws_row, float* __restrict__ partial)
{
    int bid = blockIdx.x;                    // 2 dir x 4 b x 32 slices
    const int sl  = bid & 31; bid >>= 5;
    const int b   = bid & 3;  bid >>= 2;
    const int dir = bid;

    const int p = sl * 256 + threadIdx.x;
    const float* base = ws_row + (((size_t)dir * NB + b) * SPLITS) * NPTS + p;
    float sum = fminf(fminf(base[0],        base[NPTS]),
                      fminf(base[2 * NPTS], base[3 * NPTS]));

    for (int off = 32; off; off >>= 1) sum += __shfl_down(sum, off, 64);
    __shared__ float red[4];
    if (!(threadIdx.x & 63)) red[threadIdx.x >> 6] = sum;
    __syncthreads();
    if (!threadIdx.x)
        partial[blockIdx.x] = red[0] + red[1] + red[2] + red[3];
}

// ---------- final: 4 blocks x 64 thr; each b sums its 64 partials ----------
__global__ __launch_bounds__(64) void chamfer_final(
    const float* __restrict__ partial, float* __restrict__ out)
{
    const int b = blockIdx.x, t = threadIdx.x;
    const int dir = t >> 5, sl = t & 31;
    float v = partial[(((size_t)dir * NB + b) << 5) + sl];
    for (int off = 32; off; off >>= 1) v += __shfl_down(v, off, 64);
    if (!t) out[b] = v * (1.0f / (float)NPTS);
}

extern "C" void kernel_launch(void* const* d_in, const int* in_sizes, int n_in,
                              void* d_out, int out_size, void* d_ws, size_t ws_size,
                              hipStream_t stream)
{
    const float* pc1 = (const float*)d_in[0];
    const float* pc2 = (const float*)d_in[1];
    float* out = (float*)d_out;

    char* ws = (char*)d_ws;
    half8* wsB     = (half8*)ws;                         // 2 MiB (+2-tile overrun pad into ws_row)
    float* ws_row  = (float*)(ws + (2 << 20));           // 1 MiB
    float* partial = (float*)(ws + (3 << 20));           // 1 KiB

    chamfer_prep<<<512, 256, 0, stream>>>(pc1, pc2, wsB);
    chamfer_main<<<1024, 256, 0, stream>>>(pc1, pc2, wsB, ws_row);
    chamfer_reduce<<<256, 256, 0, stream>>>(ws_row, partial);
    chamfer_final<<<NB, 64, 0, stream>>>(partial, out);
}